// Round 14
// baseline (352.747 us; speedup 1.0000x reference)
//
#include <hip/hip_runtime.h>
#include <hip/hip_bf16.h>
#include <stdint.h>

#define N_NODES 100000
#define IN_F    512
#define OUT_F   256
#define N_EDGES 1600000

typedef __attribute__((ext_vector_type(4))) float f32x4;
typedef __attribute__((ext_vector_type(8))) short bf16x8;
typedef __attribute__((ext_vector_type(8))) uint16_t u16x8;
typedef __attribute__((ext_vector_type(4))) uint32_t u32x4;

#define BM 128
#define BK 32
#define KT_TILES (IN_F / BK)             // 16
#define WFRAG_KT_STRIDE (16 * 16 * 32)   // 8192 elems per kt slab
#define EPS 66                            // epilogue LDS row stride (bf16)
#define MTILES ((N_NODES + BM - 1) / BM)  // 782

#define NBUCK 391                         // ceil(100000/256) buckets of 256 nodes
#define BCAP  4608                        // mean ~4092, +8 sigma
#define SC_EDGES 8192                     // edges per scatter block
#define NBLK_SC ((N_EDGES + SC_EDGES - 1) / SC_EDGES)   // 196

// gather slicing: h stored slice-major hs[NSLICE][N_NODES][16 cols bf16]
#define NSLICE 16
#define SLICE_ELEMS (OUT_F / NSLICE)      // 16 bf16 = 32 B per node per slice
#define GBLK_NODES 128                    // 4 waves x 32 nodes per block
#define NODE_GROUPS ((N_NODES + GBLK_NODES - 1) / GBLK_NODES)  // 782
#define GBLK_PER_PHASE (NODE_GROUPS * 8)  // 6256

__device__ __forceinline__ float bf2f(uint16_t u) {
    union { uint32_t i; float f; } c; c.i = ((uint32_t)u) << 16; return c.f;
}
__device__ __forceinline__ uint16_t f2bf(float f) {
    union { float f; uint32_t i; } c; c.f = f;
    uint32_t x = c.i;
    return (uint16_t)((x + 0x7FFFu + ((x >> 16) & 1u)) >> 16);  // RNE
}
__device__ __forceinline__ uint32_t cvt_pk_bf16(float a, float b) {
    uint32_t r;
    asm("v_cvt_pk_bf16_f32 %0, %1, %2" : "=v"(r) : "v"(a), "v"(b));
    return r;
}
// async global->LDS, 16B per lane; LDS dest = wave-uniform base + lane*16
__device__ __forceinline__ void gload_lds16(const float* g, float* l) {
    __builtin_amdgcn_global_load_lds(
        (const __attribute__((address_space(1))) void*)g,
        (__attribute__((address_space(3))) void*)l, 16, 0, 0);
}
// counted-vmcnt barrier (proven R11/R13): wait until only N vmem ops remain.
#define SYNC_VM(N) do {                                        \
    asm volatile("s_waitcnt vmcnt(" #N ")" ::: "memory");      \
    __builtin_amdgcn_s_barrier();                              \
} while (0)

// ---------------- W -> bf16 fragment-order ----------------
__global__ __launch_bounds__(256) void w_frag_kernel(
    const float* __restrict__ W, uint16_t* __restrict__ w_frag)
{
    const int gid = blockIdx.x * 256 + threadIdx.x;   // 16384 groups of 8 elems
    if (gid >= 16384) return;
    const int kg = gid & 3, lrow = (gid >> 2) & 15, cg = (gid >> 6) & 15, kt = gid >> 10;
    const float* s = W + (size_t)(cg * 16 + lrow) * IN_F + kt * 32 + kg * 8;
    const f32x4 v0 = *(const f32x4*)s;
    const f32x4 v1 = *(const f32x4*)(s + 4);
    u32x4 c;
    c[0] = cvt_pk_bf16(v0[0], v0[1]);
    c[1] = cvt_pk_bf16(v0[2], v0[3]);
    c[2] = cvt_pk_bf16(v1[0], v1[1]);
    c[3] = cvt_pk_bf16(v1[2], v1[3]);
    *(u32x4*)(w_frag + (size_t)gid * 8) = c;
}

__global__ __launch_bounds__(512) void bucket_init_kernel(int* __restrict__ bucket_cursor)
{
    const int i = threadIdx.x;
    if (i < NBUCK) bucket_cursor[i] = i * BCAP;
}

// ---------------- fused GEMM + edge-scatter ----------------
// blocks [0, MTILES): GEMM  hs = bf16(feat @ W^T + b), SLICE-MAJOR layout.
// blocks [MTILES, MTILES+NBLK_SC): scatter packed (src<<8|dst&255) into
//   padded bucket-major `pairs`.
__global__ __launch_bounds__(512) void gemm_scatter_kernel(
    const float* __restrict__ feat, const uint16_t* __restrict__ w_frag,
    const float* __restrict__ bias, uint16_t* __restrict__ hs,
    const int* __restrict__ src, const int* __restrict__ dst,
    int* __restrict__ bucket_cursor, uint32_t* __restrict__ pairs)
{
    __shared__ __align__(16) char smem_raw[3 * BM * BK * 4];   // 48 KB

    if (blockIdx.x >= MTILES) {
        // ================= scatter path =================
        int* bh    = (int*)smem_raw;           // [NBUCK]
        int* bbase = bh + NBUCK;               // [NBUCK]
        const int tid = threadIdx.x;
        for (int i = tid; i < NBUCK; i += 512) bh[i] = 0;
        __syncthreads();
        const int base = (int)(blockIdx.x - MTILES) * SC_EDGES;
        uint32_t pk[SC_EDGES / 512];
        int      bk[SC_EDGES / 512];
        #pragma unroll
        for (int k = 0; k < SC_EDGES / 512; ++k) {
            const int e = base + k * 512 + tid;
            if (e < N_EDGES) {
                const int d = dst[e], s = src[e];
                bk[k] = d >> 8;
                pk[k] = ((uint32_t)s << 8) | (uint32_t)(d & 255);
                atomicAdd(&bh[bk[k]], 1);
            } else {
                bk[k] = -1; pk[k] = 0;
            }
        }
        __syncthreads();
        for (int i = tid; i < NBUCK; i += 512) {
            const int c = bh[i];
            bbase[i] = c ? atomicAdd(&bucket_cursor[i], c) : 0;
            bh[i] = 0;
        }
        __syncthreads();
        #pragma unroll
        for (int k = 0; k < SC_EDGES / 512; ++k) {
            if (bk[k] >= 0) {
                const int r = atomicAdd(&bh[bk[k]], 1);
                pairs[bbase[bk[k]] + r] = pk[k];
            }
        }
        return;
    }

    // ================= GEMM path (R13-proven pipeline) =================
    float (*At)[BM][BK] = (float (*)[BM][BK])smem_raw;

    const int m0 = blockIdx.x * BM;

    const int t    = threadIdx.x;
    const int wid  = t >> 6;
    const int lane = t & 63;
    const int wr   = wid >> 2, wc = wid & 3;   // 2x4 waves, 64x64 tile per wave
    const int lrow = lane & 15;
    const int kg   = lane >> 4;

    f32x4 acc[4][4] = {};

    const int r8 = lane >> 3;
    const int sp = lane & 7;
    const int sc = sp ^ r8;            // source-side swizzle
    const float* gsrc[2];
    #pragma unroll
    for (int i = 0; i < 2; ++i) {
        int grow = m0 + wid * 16 + i * 8 + r8;
        if (grow > N_NODES - 1) grow = N_NODES - 1;
        gsrc[i] = feat + (size_t)grow * IN_F + sc * 4;
    }

#define STAGE(KT, BUF)                                                     \
    do {                                                                   \
        gload_lds16(gsrc[0] + (KT) * BK, &At[BUF][wid * 16][0]);           \
        gload_lds16(gsrc[1] + (KT) * BK, &At[BUF][wid * 16 + 8][0]);       \
    } while (0)

    const uint16_t* wfp[4];
    #pragma unroll
    for (int n = 0; n < 4; ++n) {
        const int cg = wc * 4 + n;
        wfp[n] = w_frag + ((size_t)cg * 16 + lrow) * 32 + kg * 8;
    }

    bf16x8 bfr[2][4];

    // prologue: B(0), stage tiles 0 and 1; single full drain
    #pragma unroll
    for (int n = 0; n < 4; ++n) bfr[0][n] = *(const bf16x8*)(wfp[n]);
    STAGE(0, 0);
    STAGE(1, 1);
    SYNC_VM(0);

    const int p0 = (2 * kg) ^ (lrow & 7);   // read-side swizzle
    const int p1 = p0 ^ 1;

    // per-iter vmem issue: 4 B-loads (kt+1) + 2 gload_lds (kt+2) = 6.
    #pragma unroll
    for (int kt = 0; kt < KT_TILES; ++kt) {
        const int cur = kt % 3;
        if (kt + 1 < KT_TILES) {
            #pragma unroll
            for (int n = 0; n < 4; ++n)
                bfr[(kt + 1) & 1][n] =
                    *(const bf16x8*)(wfp[n] + (size_t)(kt + 1) * WFRAG_KT_STRIDE);
        }
        if (kt + 2 < KT_TILES) STAGE(kt + 2, (kt + 2) % 3);

        bf16x8 af[4];
        #pragma unroll
        for (int m = 0; m < 4; ++m) {
            const int row = wr * 64 + m * 16 + lrow;
            const f32x4 v0 = *(const f32x4*)&At[cur][row][p0 * 4];
            const f32x4 v1 = *(const f32x4*)&At[cur][row][p1 * 4];
            union { bf16x8 v; uint32_t u[4]; } c_;
            c_.u[0] = cvt_pk_bf16(v0[0], v0[1]);
            c_.u[1] = cvt_pk_bf16(v0[2], v0[3]);
            c_.u[2] = cvt_pk_bf16(v1[0], v1[1]);
            c_.u[3] = cvt_pk_bf16(v1[2], v1[3]);
            af[m] = c_.v;
        }
        #pragma unroll
        for (int m = 0; m < 4; ++m)
            #pragma unroll
            for (int n = 0; n < 4; ++n)
                acc[m][n] = __builtin_amdgcn_mfma_f32_16x16x32_bf16(
                    af[m], bfr[kt & 1][n], acc[m][n], 0, 0, 0);

        if (kt <= KT_TILES - 3)       SYNC_VM(6);
        else if (kt == KT_TILES - 2)  SYNC_VM(4);
    }
#undef STAGE

    __syncthreads();   // full drain before LDS reuse

    // epilogue (R13-proven barriers): per-wave 64x64 transpose through LDS,
    // stores now target the SLICE-MAJOR hs layout.
    uint16_t* ep = (uint16_t*)smem_raw;
    const int wbase = wid * (16 * EPS);
    float bv[4];
    #pragma unroll
    for (int n = 0; n < 4; ++n) bv[n] = bias[wc * 64 + n * 16 + lrow];

    #pragma unroll
    for (int m = 0; m < 4; ++m) {
        #pragma unroll
        for (int n = 0; n < 4; ++n)
            #pragma unroll
            for (int j = 0; j < 4; ++j)
                ep[wbase + (kg * 4 + j) * EPS + n * 16 + lrow] = f2bf(acc[m][n][j] + bv[n]);
        __syncthreads();
        #pragma unroll
        for (int g = 0; g < 4; ++g) {
            const int r16  = g * 4 + (lane >> 4);
            const int cidx = (lane & 15) * 4;
            const int ib = wbase + r16 * EPS + cidx;
            uint2 v;
            v.x = *(const uint32_t*)&ep[ib];
            v.y = *(const uint32_t*)&ep[ib + 2];
            const int row = m0 + wr * 64 + m * 16 + r16;
            const int col = wc * 64 + cidx;
            const int sl  = col >> 4;          // slice
            const int c0  = col & 15;          // col within slice (0,4,8,12)
            if (row < N_NODES)
                *(uint2*)(hs + ((size_t)sl * N_NODES + row) * SLICE_ELEMS + c0) = v;
        }
        __syncthreads();
    }
}

// ---------------- per-bucket counting sort: 1 node per thread ----------------
__global__ __launch_bounds__(256) void bucket_sort_kernel(
    const uint32_t* __restrict__ pairs, const int* __restrict__ bucket_cursor,
    int* __restrict__ start, int* __restrict__ deg, int* __restrict__ csr_src)
{
    __shared__ int hist[256];
    __shared__ int cur[256];
    __shared__ int tsum[256];
    const int b = blockIdx.x;
    const int t = threadIdx.x;
    const int ebeg = b * BCAP;
    const int eend = bucket_cursor[b];   // = b*BCAP + count after scatter
    hist[t] = 0;
    __syncthreads();
    for (int i = ebeg + t; i < eend; i += 256)
        atomicAdd(&hist[pairs[i] & 255], 1);
    __syncthreads();
    const int c = hist[t];
    int x = c;
    tsum[t] = x; __syncthreads();
    for (int off = 1; off < 256; off <<= 1) {
        const int y = (t >= off) ? tsum[t - off] : 0;
        __syncthreads();
        x += y; tsum[t] = x;
        __syncthreads();
    }
    const int ex = x - c;               // exclusive prefix
    const int node = (b << 8) + t;
    if (node < N_NODES) {
        start[node] = ebeg + ex;
        deg[node]   = c;
    }
    cur[t] = ebeg + ex;
    __syncthreads();
    for (int i = ebeg + t; i < eend; i += 256) {
        const uint32_t p = pairs[i];
        const int pos = atomicAdd(&cur[p & 255], 1);
        csr_src[pos] = (int)(p >> 8);
    }
}

// ---------------- gather v5: XCD-pinned slice-resident ----------------
// hs is slice-major [NSLICE][N_NODES][16]. Each XCD (blockIdx%8 heuristic)
// processes one 3.2 MB slice per phase -> L2-resident. Wave = 32 nodes x
// 1 slice; lane pair per node (16 B/lane); wave-max-deg loop, 2-unrolled.
// out stores nontemporal to avoid evicting the h slice.
__global__ __launch_bounds__(256) void gcn_gather_kernel(
    const uint16_t* __restrict__ hs, const int* __restrict__ start,
    const int* __restrict__ deg, const int* __restrict__ csr_src,
    float* __restrict__ out)
{
    const int b = blockIdx.x;
    const int phase = (b >= GBLK_PER_PHASE) ? 1 : 0;
    const int q = b - phase * GBLK_PER_PHASE;
    const int s = (q & 7) | (phase << 3);    // slice; q&7 pins slice->XCD
    const int ng = q >> 3;                   // node group 0..781
    const int w = threadIdx.x >> 6;
    const int lane = threadIdx.x & 63;
    const int p = lane >> 1;                 // node within 32
    const int ch = lane & 1;                 // 16-B half of 32-B slice row
    const int n = ng * GBLK_NODES + w * 32 + p;
    const bool ok = n < N_NODES;
    const int beg = ok ? start[n] : 0;
    const int dg  = ok ? deg[n] : 0;

    // wave max degree (all lanes participate; no early return)
    int m = dg;
    #pragma unroll
    for (int off = 1; off < 64; off <<= 1)
        m = max(m, __shfl_xor(m, off, 64));

    const uint16_t* hb = hs + (size_t)s * N_NODES * SLICE_ELEMS + ch * 8;

    float a[8] = {0.f, 0.f, 0.f, 0.f, 0.f, 0.f, 0.f, 0.f};

    for (int j = 0; j < m; j += 2) {
        u16x8 v0 = {}, v1 = {};
        if (j < dg)
            v0 = *(const u16x8*)(hb + (size_t)csr_src[beg + j] * SLICE_ELEMS);
        if (j + 1 < dg)
            v1 = *(const u16x8*)(hb + (size_t)csr_src[beg + j + 1] * SLICE_ELEMS);
        #pragma unroll
        for (int i = 0; i < 8; ++i) a[i] += bf2f(v0[i]);
        #pragma unroll
        for (int i = 0; i < 8; ++i) a[i] += bf2f(v1[i]);
    }

    if (ok) {
        float* op = out + (size_t)n * OUT_F + s * SLICE_ELEMS + ch * 8;
        f32x4 o0, o1;
        o0[0] = a[0]; o0[1] = a[1]; o0[2] = a[2]; o0[3] = a[3];
        o1[0] = a[4]; o1[1] = a[5]; o1[2] = a[6]; o1[3] = a[7];
        __builtin_nontemporal_store(o0, (f32x4*)op);
        __builtin_nontemporal_store(o1, (f32x4*)(op + 4));
    }
}

// ---------------- fallback: atomic scatter (tiny ws; slice-major hs) --------
__global__ __launch_bounds__(256) void gcn_scatter_kernel(
    const uint16_t* __restrict__ hs, const int* __restrict__ src,
    const int* __restrict__ dst, float* __restrict__ out)
{
    const int e = (blockIdx.x << 2) | (threadIdx.x >> 6);
    if (e >= N_EDGES) return;
    const int lane = threadIdx.x & 63;
    const int s = src[e];
    const int d = dst[e];
    const int sl = lane >> 2;               // slice
    const int c0 = (lane & 3) * 4;          // col in slice
    const ushort4 v = *(const ushort4*)(hs + ((size_t)sl * N_NODES + s) * SLICE_ELEMS + c0);
    float* op = out + (size_t)d * OUT_F + sl * SLICE_ELEMS + c0;
    unsafeAtomicAdd(op + 0, bf2f(v.x));
    unsafeAtomicAdd(op + 1, bf2f(v.y));
    unsafeAtomicAdd(op + 2, bf2f(v.z));
    unsafeAtomicAdd(op + 3, bf2f(v.w));
}

static inline size_t align256(size_t x) { return (x + 255) & ~(size_t)255; }

extern "C" void kernel_launch(void* const* d_in, const int* in_sizes, int n_in,
                              void* d_out, int out_size, void* d_ws, size_t ws_size,
                              hipStream_t stream) {
    const float* feat = (const float*)d_in[0];
    const float* W    = (const float*)d_in[1];
    const float* bias = (const float*)d_in[2];
    const int*   src  = (const int*)d_in[3];
    const int*   dst  = (const int*)d_in[4];
    float*       out  = (float*)d_out;

    char* ws = (char*)d_ws;

    size_t off = 0;
    uint16_t* hs      = (uint16_t*)(ws + off); off = align256(off + (size_t)N_NODES * OUT_F * 2);
    uint16_t* w_frag  = (uint16_t*)(ws + off); off = align256(off + (size_t)OUT_F * IN_F * 2);
    int* start        = (int*)(ws + off);      off = align256(off + (size_t)N_NODES * 4);
    int* deg          = (int*)(ws + off);      off = align256(off + (size_t)N_NODES * 4);
    int* bucket_cursor= (int*)(ws + off);      off = align256(off + (size_t)NBUCK * 4);
    uint32_t* pairs   = (uint32_t*)(ws + off); off = align256(off + (size_t)NBUCK * BCAP * 4);
    int* csr_src      = (int*)(ws + off);      off = align256(off + (size_t)NBUCK * BCAP * 4);
    const bool bucket_ok = (off <= ws_size);

    w_frag_kernel<<<64, 256, 0, stream>>>(W, w_frag);

    if (bucket_ok) {
        bucket_init_kernel<<<1, 512, 0, stream>>>(bucket_cursor);
        gemm_scatter_kernel<<<MTILES + NBLK_SC, 512, 0, stream>>>(
            feat, w_frag, bias, hs, src, dst, bucket_cursor, pairs);
        bucket_sort_kernel<<<NBUCK, 256, 0, stream>>>(pairs, bucket_cursor, start, deg, csr_src);
        gcn_gather_kernel<<<2 * GBLK_PER_PHASE, 256, 0, stream>>>(hs, start, deg, csr_src, out);
    } else {
        gemm_scatter_kernel<<<MTILES, 512, 0, stream>>>(
            feat, w_frag, bias, hs, src, dst, (int*)d_ws, (uint32_t*)d_ws);
        hipMemsetAsync(out, 0, (size_t)out_size * sizeof(float), stream);
        gcn_scatter_kernel<<<(N_EDGES + 3) / 4, 256, 0, stream>>>(hs, src, dst, out);
    }
}

// Round 15
// 204.101 us; speedup vs baseline: 1.7283x; 1.7283x over previous
//
#include <hip/hip_runtime.h>
#include <hip/hip_bf16.h>
#include <stdint.h>

#define N_NODES 100000
#define IN_F    512
#define OUT_F   256
#define N_EDGES 1600000

typedef __attribute__((ext_vector_type(4))) float f32x4;
typedef __attribute__((ext_vector_type(8))) short bf16x8;
typedef __attribute__((ext_vector_type(8))) uint16_t u16x8;
typedef __attribute__((ext_vector_type(4))) uint32_t u32x4;

#define BM 128
#define BK 32
#define KT_TILES (IN_F / BK)             // 16
#define WFRAG_KT_STRIDE (16 * 16 * 32)   // 8192 elems per kt slab
#define EPS 66                            // epilogue LDS row stride (bf16)
#define MTILES ((N_NODES + BM - 1) / BM)  // 782

#define NBUCK 391                         // ceil(100000/256) buckets of 256 nodes
#define BCAP  4608                        // mean ~4092, +8 sigma
#define SC_EDGES 8192                     // edges per scatter block
#define NBLK_SC ((N_EDGES + SC_EDGES - 1) / SC_EDGES)   // 196

__device__ __forceinline__ float bf2f(uint16_t u) {
    union { uint32_t i; float f; } c; c.i = ((uint32_t)u) << 16; return c.f;
}
__device__ __forceinline__ uint16_t f2bf(float f) {
    union { float f; uint32_t i; } c; c.f = f;
    uint32_t x = c.i;
    return (uint16_t)((x + 0x7FFFu + ((x >> 16) & 1u)) >> 16);  // RNE
}
__device__ __forceinline__ uint32_t cvt_pk_bf16(float a, float b) {
    uint32_t r;
    asm("v_cvt_pk_bf16_f32 %0, %1, %2" : "=v"(r) : "v"(a), "v"(b));
    return r;
}
// async global->LDS, 16B per lane; LDS dest = wave-uniform base + lane*16
__device__ __forceinline__ void gload_lds16(const float* g, float* l) {
    __builtin_amdgcn_global_load_lds(
        (const __attribute__((address_space(1))) void*)g,
        (__attribute__((address_space(3))) void*)l, 16, 0, 0);
}
// counted-vmcnt barrier (proven R11/R13): wait until only N vmem ops remain.
#define SYNC_VM(N) do {                                        \
    asm volatile("s_waitcnt vmcnt(" #N ")" ::: "memory");      \
    __builtin_amdgcn_s_barrier();                              \
} while (0)

// ---------------- W -> bf16 fragment-order (+ fused bucket_init) -------------
__global__ __launch_bounds__(256) void w_frag_kernel(
    const float* __restrict__ W, uint16_t* __restrict__ w_frag,
    int* __restrict__ bucket_cursor)
{
    const int gid = blockIdx.x * 256 + threadIdx.x;   // 16384 groups of 8 elems
    if (gid < NBUCK) bucket_cursor[gid] = gid * BCAP; // independent init
    if (gid >= 16384) return;
    const int kg = gid & 3, lrow = (gid >> 2) & 15, cg = (gid >> 6) & 15, kt = gid >> 10;
    const float* s = W + (size_t)(cg * 16 + lrow) * IN_F + kt * 32 + kg * 8;
    const f32x4 v0 = *(const f32x4*)s;
    const f32x4 v1 = *(const f32x4*)(s + 4);
    u32x4 c;
    c[0] = cvt_pk_bf16(v0[0], v0[1]);
    c[1] = cvt_pk_bf16(v0[2], v0[3]);
    c[2] = cvt_pk_bf16(v1[0], v1[1]);
    c[3] = cvt_pk_bf16(v1[2], v1[3]);
    *(u32x4*)(w_frag + (size_t)gid * 8) = c;
}

// ---------------- fused GEMM + edge-scatter (R13-proven) ----------------
// blocks [0, MTILES): GEMM  h = bf16(feat @ W^T + b), row-major h.
// blocks [MTILES, MTILES+NBLK_SC): scatter packed (src<<8|dst&255) into
//   padded bucket-major `pairs`.
__global__ __launch_bounds__(512) void gemm_scatter_kernel(
    const float* __restrict__ feat, const uint16_t* __restrict__ w_frag,
    const float* __restrict__ bias, uint16_t* __restrict__ h,
    const int* __restrict__ src, const int* __restrict__ dst,
    int* __restrict__ bucket_cursor, uint32_t* __restrict__ pairs)
{
    __shared__ __align__(16) char smem_raw[3 * BM * BK * 4];   // 48 KB

    if (blockIdx.x >= MTILES) {
        // ================= scatter path =================
        int* bh    = (int*)smem_raw;           // [NBUCK]
        int* bbase = bh + NBUCK;               // [NBUCK]
        const int tid = threadIdx.x;
        for (int i = tid; i < NBUCK; i += 512) bh[i] = 0;
        __syncthreads();
        const int base = (int)(blockIdx.x - MTILES) * SC_EDGES;
        uint32_t pk[SC_EDGES / 512];
        int      bk[SC_EDGES / 512];
        #pragma unroll
        for (int k = 0; k < SC_EDGES / 512; ++k) {
            const int e = base + k * 512 + tid;
            if (e < N_EDGES) {
                const int d = dst[e], s = src[e];
                bk[k] = d >> 8;
                pk[k] = ((uint32_t)s << 8) | (uint32_t)(d & 255);
                atomicAdd(&bh[bk[k]], 1);
            } else {
                bk[k] = -1; pk[k] = 0;
            }
        }
        __syncthreads();
        for (int i = tid; i < NBUCK; i += 512) {
            const int c = bh[i];
            bbase[i] = c ? atomicAdd(&bucket_cursor[i], c) : 0;
            bh[i] = 0;
        }
        __syncthreads();
        #pragma unroll
        for (int k = 0; k < SC_EDGES / 512; ++k) {
            if (bk[k] >= 0) {
                const int r = atomicAdd(&bh[bk[k]], 1);
                pairs[bbase[bk[k]] + r] = pk[k];
            }
        }
        return;
    }

    // ================= GEMM path =================
    float (*At)[BM][BK] = (float (*)[BM][BK])smem_raw;

    const int m0 = blockIdx.x * BM;

    const int t    = threadIdx.x;
    const int wid  = t >> 6;
    const int lane = t & 63;
    const int wr   = wid >> 2, wc = wid & 3;   // 2x4 waves, 64x64 tile per wave
    const int lrow = lane & 15;
    const int kg   = lane >> 4;

    f32x4 acc[4][4] = {};

    const int r8 = lane >> 3;
    const int sp = lane & 7;
    const int sc = sp ^ r8;            // source-side swizzle
    const float* gsrc[2];
    #pragma unroll
    for (int i = 0; i < 2; ++i) {
        int grow = m0 + wid * 16 + i * 8 + r8;
        if (grow > N_NODES - 1) grow = N_NODES - 1;
        gsrc[i] = feat + (size_t)grow * IN_F + sc * 4;
    }

#define STAGE(KT, BUF)                                                     \
    do {                                                                   \
        gload_lds16(gsrc[0] + (KT) * BK, &At[BUF][wid * 16][0]);           \
        gload_lds16(gsrc[1] + (KT) * BK, &At[BUF][wid * 16 + 8][0]);       \
    } while (0)

    const uint16_t* wfp[4];
    #pragma unroll
    for (int n = 0; n < 4; ++n) {
        const int cg = wc * 4 + n;
        wfp[n] = w_frag + ((size_t)cg * 16 + lrow) * 32 + kg * 8;
    }

    bf16x8 bfr[2][4];

    // prologue: B(0), stage tiles 0 and 1; single full drain
    #pragma unroll
    for (int n = 0; n < 4; ++n) bfr[0][n] = *(const bf16x8*)(wfp[n]);
    STAGE(0, 0);
    STAGE(1, 1);
    SYNC_VM(0);

    const int p0 = (2 * kg) ^ (lrow & 7);   // read-side swizzle
    const int p1 = p0 ^ 1;

    // per-iter vmem issue: 4 B-loads (kt+1) + 2 gload_lds (kt+2) = 6.
    #pragma unroll
    for (int kt = 0; kt < KT_TILES; ++kt) {
        const int cur = kt % 3;
        if (kt + 1 < KT_TILES) {
            #pragma unroll
            for (int n = 0; n < 4; ++n)
                bfr[(kt + 1) & 1][n] =
                    *(const bf16x8*)(wfp[n] + (size_t)(kt + 1) * WFRAG_KT_STRIDE);
        }
        if (kt + 2 < KT_TILES) STAGE(kt + 2, (kt + 2) % 3);

        bf16x8 af[4];
        #pragma unroll
        for (int m = 0; m < 4; ++m) {
            const int row = wr * 64 + m * 16 + lrow;
            const f32x4 v0 = *(const f32x4*)&At[cur][row][p0 * 4];
            const f32x4 v1 = *(const f32x4*)&At[cur][row][p1 * 4];
            union { bf16x8 v; uint32_t u[4]; } c_;
            c_.u[0] = cvt_pk_bf16(v0[0], v0[1]);
            c_.u[1] = cvt_pk_bf16(v0[2], v0[3]);
            c_.u[2] = cvt_pk_bf16(v1[0], v1[1]);
            c_.u[3] = cvt_pk_bf16(v1[2], v1[3]);
            af[m] = c_.v;
        }
        #pragma unroll
        for (int m = 0; m < 4; ++m)
            #pragma unroll
            for (int n = 0; n < 4; ++n)
                acc[m][n] = __builtin_amdgcn_mfma_f32_16x16x32_bf16(
                    af[m], bfr[kt & 1][n], acc[m][n], 0, 0, 0);

        if (kt <= KT_TILES - 3)       SYNC_VM(6);
        else if (kt == KT_TILES - 2)  SYNC_VM(4);
    }
#undef STAGE

    __syncthreads();   // full drain before LDS reuse

    // epilogue (R13-proven barriers): per-wave 64x64 transpose through LDS.
    uint16_t* ep = (uint16_t*)smem_raw;
    const int wbase = wid * (16 * EPS);
    float bv[4];
    #pragma unroll
    for (int n = 0; n < 4; ++n) bv[n] = bias[wc * 64 + n * 16 + lrow];

    #pragma unroll
    for (int m = 0; m < 4; ++m) {
        #pragma unroll
        for (int n = 0; n < 4; ++n)
            #pragma unroll
            for (int j = 0; j < 4; ++j)
                ep[wbase + (kg * 4 + j) * EPS + n * 16 + lrow] = f2bf(acc[m][n][j] + bv[n]);
        __syncthreads();
        #pragma unroll
        for (int g = 0; g < 4; ++g) {
            const int r16  = g * 4 + (lane >> 4);
            const int cidx = (lane & 15) * 4;
            const int ib = wbase + r16 * EPS + cidx;
            uint2 v;
            v.x = *(const uint32_t*)&ep[ib];
            v.y = *(const uint32_t*)&ep[ib + 2];
            const int row = m0 + wr * 64 + m * 16 + r16;
            if (row < N_NODES)
                *(uint2*)(h + (size_t)row * OUT_F + wc * 64 + cidx) = v;
        }
        __syncthreads();
    }
}

// ---------------- per-bucket counting sort: 1 node per thread ----------------
__global__ __launch_bounds__(256) void bucket_sort_kernel(
    const uint32_t* __restrict__ pairs, const int* __restrict__ bucket_cursor,
    int* __restrict__ start, int* __restrict__ deg, int* __restrict__ csr_src)
{
    __shared__ int hist[256];
    __shared__ int cur[256];
    __shared__ int tsum[256];
    const int b = blockIdx.x;
    const int t = threadIdx.x;
    const int ebeg = b * BCAP;
    const int eend = bucket_cursor[b];   // = b*BCAP + count after scatter
    hist[t] = 0;
    __syncthreads();
    for (int i = ebeg + t; i < eend; i += 256)
        atomicAdd(&hist[pairs[i] & 255], 1);
    __syncthreads();
    const int c = hist[t];
    int x = c;
    tsum[t] = x; __syncthreads();
    for (int off = 1; off < 256; off <<= 1) {
        const int y = (t >= off) ? tsum[t - off] : 0;
        __syncthreads();
        x += y; tsum[t] = x;
        __syncthreads();
    }
    const int ex = x - c;               // exclusive prefix
    const int node = (b << 8) + t;
    if (node < N_NODES) {
        start[node] = ebeg + ex;
        deg[node]   = c;
    }
    cur[t] = ebeg + ex;
    __syncthreads();
    for (int i = ebeg + t; i < eend; i += 256) {
        const uint32_t p = pairs[i];
        const int pos = atomicAdd(&cur[p & 255], 1);
        csr_src[pos] = (int)(p >> 8);
    }
}

// ---------------- gather (R13-proven v2) + nontemporal out stores ------------
__global__ __launch_bounds__(256) void gcn_gather_kernel(
    const uint16_t* __restrict__ h, const int* __restrict__ start,
    const int* __restrict__ deg, const int* __restrict__ csr_src,
    float* __restrict__ out)
{
    const int n = blockIdx.x * 4 + (threadIdx.x >> 6);
    if (n >= N_NODES) return;
    const int lane = threadIdx.x & 63;
    const int half = lane >> 5;
    const int hl   = lane & 31;
    const int beg = start[n];
    const int end = beg + deg[n];

    float a[8] = {0.f, 0.f, 0.f, 0.f, 0.f, 0.f, 0.f, 0.f};

    int j = beg + half;
    for (; j + 2 < end; j += 4) {
        const int s0 = csr_src[j];
        const int s1 = csr_src[j + 2];
        const u16x8 v0 = *(const u16x8*)(h + (size_t)s0 * OUT_F + hl * 8);
        const u16x8 v1 = *(const u16x8*)(h + (size_t)s1 * OUT_F + hl * 8);
        #pragma unroll
        for (int i = 0; i < 8; ++i) a[i] += bf2f(v0[i]);
        #pragma unroll
        for (int i = 0; i < 8; ++i) a[i] += bf2f(v1[i]);
    }
    if (j < end) {
        const int s0 = csr_src[j];
        const u16x8 v0 = *(const u16x8*)(h + (size_t)s0 * OUT_F + hl * 8);
        #pragma unroll
        for (int i = 0; i < 8; ++i) a[i] += bf2f(v0[i]);
    }

    #pragma unroll
    for (int i = 0; i < 8; ++i) a[i] += __shfl_xor(a[i], 32, 64);

    if (half == 0) {
        f32x4 o0, o1;
        o0[0] = a[0]; o0[1] = a[1]; o0[2] = a[2]; o0[3] = a[3];
        o1[0] = a[4]; o1[1] = a[5]; o1[2] = a[6]; o1[3] = a[7];
        float* op = out + (size_t)n * OUT_F + hl * 8;
        // write-once stream: nontemporal so the 102 MB out write doesn't
        // evict cached h lines (h reuse ~16x is what keeps FETCH at 380 MB).
        __builtin_nontemporal_store(o0, (f32x4*)op);
        __builtin_nontemporal_store(o1, (f32x4*)(op + 4));
    }
}

// ---------------- fallback: atomic scatter (tiny ws) ------------
__global__ __launch_bounds__(256) void gcn_scatter_kernel(
    const uint16_t* __restrict__ h, const int* __restrict__ src,
    const int* __restrict__ dst, float* __restrict__ out)
{
    const int e = (blockIdx.x << 2) | (threadIdx.x >> 6);
    if (e >= N_EDGES) return;
    const int lane = threadIdx.x & 63;
    const int s = src[e];
    const int d = dst[e];
    const ushort4 v = *((const ushort4*)(h + (size_t)s * OUT_F) + lane);
    float* op = out + (size_t)d * OUT_F + (lane << 2);
    unsafeAtomicAdd(op + 0, bf2f(v.x));
    unsafeAtomicAdd(op + 1, bf2f(v.y));
    unsafeAtomicAdd(op + 2, bf2f(v.z));
    unsafeAtomicAdd(op + 3, bf2f(v.w));
}

static inline size_t align256(size_t x) { return (x + 255) & ~(size_t)255; }

extern "C" void kernel_launch(void* const* d_in, const int* in_sizes, int n_in,
                              void* d_out, int out_size, void* d_ws, size_t ws_size,
                              hipStream_t stream) {
    const float* feat = (const float*)d_in[0];
    const float* W    = (const float*)d_in[1];
    const float* bias = (const float*)d_in[2];
    const int*   src  = (const int*)d_in[3];
    const int*   dst  = (const int*)d_in[4];
    float*       out  = (float*)d_out;

    char* ws = (char*)d_ws;

    size_t off = 0;
    uint16_t* h       = (uint16_t*)(ws + off); off = align256(off + (size_t)N_NODES * OUT_F * 2);
    uint16_t* w_frag  = (uint16_t*)(ws + off); off = align256(off + (size_t)OUT_F * IN_F * 2);
    int* start        = (int*)(ws + off);      off = align256(off + (size_t)N_NODES * 4);
    int* deg          = (int*)(ws + off);      off = align256(off + (size_t)N_NODES * 4);
    int* bucket_cursor= (int*)(ws + off);      off = align256(off + (size_t)NBUCK * 4);
    uint32_t* pairs   = (uint32_t*)(ws + off); off = align256(off + (size_t)NBUCK * BCAP * 4);
    int* csr_src      = (int*)(ws + off);      off = align256(off + (size_t)NBUCK * BCAP * 4);
    const bool bucket_ok = (off <= ws_size);

    w_frag_kernel<<<64, 256, 0, stream>>>(W, w_frag, bucket_cursor);

    if (bucket_ok) {
        gemm_scatter_kernel<<<MTILES + NBLK_SC, 512, 0, stream>>>(
            feat, w_frag, bias, h, src, dst, bucket_cursor, pairs);
        bucket_sort_kernel<<<NBUCK, 256, 0, stream>>>(pairs, bucket_cursor, start, deg, csr_src);
        gcn_gather_kernel<<<(N_NODES + 3) / 4, 256, 0, stream>>>(h, start, deg, csr_src, out);
    } else {
        gemm_scatter_kernel<<<MTILES, 512, 0, stream>>>(
            feat, w_frag, bias, h, src, dst, (int*)d_ws, (uint32_t*)d_ws);
        hipMemsetAsync(out, 0, (size_t)out_size * sizeof(float), stream);
        gcn_scatter_kernel<<<(N_EDGES + 3) / 4, 256, 0, stream>>>(h, src, dst, out);
    }
}